// Round 23
// baseline (1988.019 us; speedup 1.0000x reference)
//
#include <hip/hip_runtime.h>
#include <cstdint>

#define Bn 2048
#define Dn 4096
#define Fn 32768
#define KTOP 64
#define MCAND 192
#define KCB 512    // BLIS/AOCL zen sgemm KC
#define DCAP 4096  // disputed-candidate list capacity

typedef __attribute__((ext_vector_type(8))) short short8;
typedef __attribute__((ext_vector_type(4))) float f32x4;
typedef __attribute__((ext_vector_type(8))) unsigned short u16x8;

typedef __attribute__((address_space(1))) void as1_void;
typedef __attribute__((address_space(3))) void as3_void;

__device__ __forceinline__ void gload_lds16(const void* g, void* l) {
  __builtin_amdgcn_global_load_lds((const as1_void*)(uintptr_t)g,
                                   (as3_void*)(unsigned int)(uintptr_t)l,
                                   16, 0, 0);
}

__device__ __forceinline__ float bf2f(unsigned short u) {
  unsigned int x = ((unsigned int)u) << 16;
  return __builtin_bit_cast(float, x);
}
__device__ __forceinline__ unsigned short f2bf(float f) {
  unsigned int x = __builtin_bit_cast(unsigned int, f);
  x = x + 0x7fffu + ((x >> 16) & 1u);
  return (unsigned short)(x >> 16);
}

// ---------------- fp32 -> bf16 convert, 8 elems/thread ----------------
__global__ __launch_bounds__(256) void k_cvt_bf16(const float* __restrict__ in,
                                                  unsigned short* __restrict__ out,
                                                  long n8) {
  const long i = (long)blockIdx.x * 256 + threadIdx.x;
  if (i >= n8) return;
  const float4 a = *(const float4*)(in + i * 8);
  const float4 b = *(const float4*)(in + i * 8 + 4);
  uint4 o;
  o.x = (unsigned int)f2bf(a.x) | ((unsigned int)f2bf(a.y) << 16);
  o.y = (unsigned int)f2bf(a.z) | ((unsigned int)f2bf(a.w) << 16);
  o.z = (unsigned int)f2bf(b.x) | ((unsigned int)f2bf(b.y) << 16);
  o.w = (unsigned int)f2bf(b.z) | ((unsigned int)f2bf(b.w) << 16);
  *(uint4*)(out + i * 8) = o;
}

// ---------------- encoder GEMM: Hb[M,N] (bf16) = Xbf[M,K] * Wbf[N,K]^T + bias ----------------
// BM=256 x BN=128, BK=64, 512 threads (8 waves = 4m x 2n). R20/R22-verified
// structure (MfmaUtil 50%). bf16 epilogue store.
__global__ __launch_bounds__(512) void k_gemm_encode(
    const unsigned short* __restrict__ A,   // M x K bf16 (x)
    const unsigned short* __restrict__ Bm,  // N x K bf16 (W_enc)
    const float* __restrict__ bias,         // N (b_enc)
    unsigned short* __restrict__ Hb)        // M x N bf16
{
  constexpr int Kd = Dn;
  constexpr int Nn = Fn;
  __shared__ __align__(16) unsigned short lA[256 * 64];  // 32 KB
  __shared__ __align__(16) unsigned short lB[128 * 64];  // 16 KB
  const int tid = threadIdx.x;
  const int lane = tid & 63;
  const int wid = tid >> 6;                 // 0..7
  const int wm = wid >> 1, wn = wid & 1;    // 4 x 2 wave grid
  const int m0 = blockIdx.x * 256;
  const int n0 = blockIdx.y * 128;

  const int srow = lane >> 3;                   // 0..7 row within 8-row section
  const int csw = ((lane & 7) ^ srow) * 8;      // swizzled k-element offset (bf16 units)

  f32x4 acc[4][4] = {};

  for (int kt = 0; kt < Kd; kt += 64) {
    // 48 sections (32 A + 16 B), 6 per wave; section = 8 rows x 64 cols
#pragma unroll
    for (int s = wid; s < 48; s += 8) {
      if (s < 32) {
        const int r = s * 8 + srow;
        gload_lds16(A + (size_t)(m0 + r) * Kd + kt + csw, (char*)lA + s * 1024);
      } else {
        const int s2 = s - 32;
        const int r = s2 * 8 + srow;
        gload_lds16(Bm + (size_t)(n0 + r) * Kd + kt + csw, (char*)lB + s2 * 1024);
      }
    }
    __syncthreads();
#pragma unroll
    for (int kk = 0; kk < 2; ++kk) {
      short8 af[4], bfr[4];
      const int c16 = (kk * 4 + (lane >> 4)) ^ (lane & 7);
#pragma unroll
      for (int i = 0; i < 4; ++i) {
        const int row = wm * 64 + i * 16 + (lane & 15);
        af[i] = *(const short8*)((const char*)lA + row * 128 + c16 * 16);
      }
#pragma unroll
      for (int j = 0; j < 4; ++j) {
        const int row = wn * 64 + j * 16 + (lane & 15);
        bfr[j] = *(const short8*)((const char*)lB + row * 128 + c16 * 16);
      }
#pragma unroll
      for (int i = 0; i < 4; ++i)
#pragma unroll
        for (int j = 0; j < 4; ++j)
          acc[i][j] = __builtin_amdgcn_mfma_f32_16x16x32_bf16(af[i], bfr[j], acc[i][j], 0, 0, 0);
    }
    __syncthreads();
  }

  const int lr = (lane >> 4) * 4;
  const int lc = lane & 15;
#pragma unroll
  for (int i = 0; i < 4; ++i) {
    const int grow = m0 + wm * 64 + i * 16 + lr;
#pragma unroll
    for (int j = 0; j < 4; ++j) {
      const int gcol = n0 + wn * 64 + j * 16 + lc;
      const float bv = bias[gcol];
#pragma unroll
      for (int r = 0; r < 4; ++r)
        Hb[(size_t)(grow + r) * Nn + gcol] = f2bf(acc[i][j][r] + bv);
    }
  }
}

// ---------------- per-row candidate selection; LDS row cache (bf16 H) ----------------
// Pass 1 streams the row from global (histogram) AND stores it to LDS;
// pass 2 reads LDS -> kernel global traffic halves. Margin 0.08 (R22-proven:
// covers bf16-GEMM tail ~0.03 + bf16-H quantization <=0.0156 with headroom).
__global__ __launch_bounds__(256) void k_topk_select(
    const unsigned short* __restrict__ Hb, int* __restrict__ cand_idx,
    int* __restrict__ cand_cnt, int* __restrict__ feat_cnt,
    int* __restrict__ feat_list, float* __restrict__ cand_v32,
    double* __restrict__ cand_v64)
{
  __shared__ __align__(16) unsigned short srow[Fn];  // 64 KB
  __shared__ int hist[2048];
  __shared__ float s_tau;
  __shared__ int s_cnt;
  const int b = blockIdx.x;
  const int t = threadIdx.x;
  for (int i = t; i < 2048; i += 256) hist[i] = 0;
  if (t == 0) s_cnt = 0;
  __syncthreads();
  const unsigned short* row = Hb + (size_t)b * Fn;
  for (int i = t * 8; i < Fn; i += 2048) {
    const u16x8 hv = *(const u16x8*)(row + i);
    *(u16x8*)(srow + i) = hv;
#pragma unroll
    for (int q = 0; q < 8; ++q) {
      const float h = bf2f(hv[q]);
      if (h > 0.0f) {
        int bin = (int)(h * 128.0f);
        if (bin > 2047) bin = 2047;
        atomicAdd(&hist[bin], 1);
      }
    }
  }
  __syncthreads();
  if (t == 0) {
    int total = 0;
    int bin = 2047;
    for (; bin > 0; --bin) {
      total += hist[bin];
      if (total >= KTOP) break;
    }
    s_tau = (float)bin * (1.0f / 128.0f) - 0.08f;
  }
  __syncthreads();
  const float tau = s_tau;
  for (int i = t * 8; i < Fn; i += 2048) {
    const u16x8 hv = *(const u16x8*)(srow + i);
#pragma unroll
    for (int q = 0; q < 8; ++q) {
      const float h = bf2f(hv[q]);
      if (h >= tau) {
        const int pos = atomicAdd(&s_cnt, 1);
        if (pos < MCAND) {
          cand_idx[(size_t)b * MCAND + pos] = i + q;
          const int slot = atomicAdd(&feat_cnt[i + q], 1);
          if (slot < 64) feat_list[(size_t)(i + q) * 64 + slot] = (b << 8) | pos;
          else {  // overflow sentinel, never stale
            cand_v32[(size_t)b * MCAND + pos] = -1e30f;
            cand_v64[(size_t)b * MCAND + pos] = -1e30;
          }
        }
      }
    }
  }
  __syncthreads();
  if (t == 0) cand_cnt[b] = s_cnt < MCAND ? s_cnt : MCAND;
}

// ---------------- fp64 coalesced recompute, 2 candidates per wave-step ----------------
// Two candidates of the same feature share the W chunk: load wv once, run two
// independent fp64 FMA chains -> W L1 reads halve, 2x loads in flight.
// Per-candidate arithmetic identical to R22 (bit-identical values).
__global__ __launch_bounds__(256) void k_exact_rank(
    const float* __restrict__ x, const float* __restrict__ W,
    const float* __restrict__ b_enc, const int* __restrict__ feat_cnt,
    const int* __restrict__ feat_list, float* __restrict__ cand_v32,
    double* __restrict__ cand_v64)
{
  const int f = blockIdx.x * 4 + (threadIdx.x >> 6);
  const int lane = threadIdx.x & 63;
  int c = feat_cnt[f];
  if (c > 64) c = 64;
  if (c == 0) return;
  const float* wr = W + (size_t)f * Dn;
  const double bias = (double)b_enc[f];
  for (int e = 0; e < c; e += 2) {
    const int ent0 = feat_list[(size_t)f * 64 + e];
    const bool has1 = (e + 1 < c);
    const int ent1 = has1 ? feat_list[(size_t)f * 64 + e + 1] : ent0;
    const int b0 = ent0 >> 8, pos0 = ent0 & 255;
    const int b1 = ent1 >> 8, pos1 = ent1 & 255;
    const float* xr0 = x + (size_t)b0 * Dn;
    const float* xr1 = x + (size_t)b1 * Dn;
    double s0 = 0.0, s1 = 0.0;
#pragma unroll
    for (int k = 0; k < Dn / 256; ++k) {
      const f32x4 wv = *(const f32x4*)(wr + k * 256 + lane * 4);
      const f32x4 x0 = *(const f32x4*)(xr0 + k * 256 + lane * 4);
      const f32x4 x1 = *(const f32x4*)(xr1 + k * 256 + lane * 4);
      s0 = fma((double)x0[0], (double)wv[0], s0);
      s0 = fma((double)x0[1], (double)wv[1], s0);
      s0 = fma((double)x0[2], (double)wv[2], s0);
      s0 = fma((double)x0[3], (double)wv[3], s0);
      s1 = fma((double)x1[0], (double)wv[0], s1);
      s1 = fma((double)x1[1], (double)wv[1], s1);
      s1 = fma((double)x1[2], (double)wv[2], s1);
      s1 = fma((double)x1[3], (double)wv[3], s1);
    }
    for (int o = 32; o > 0; o >>= 1) {
      s0 += __shfl_down(s0, o);
      s1 += __shfl_down(s1, o);
    }
    if (lane == 0) {
      const double v0 = s0 + bias;
      cand_v64[(size_t)b0 * MCAND + pos0] = v0;
      cand_v32[(size_t)b0 * MCAND + pos0] = (float)v0;
      if (has1) {
        const double v1 = s1 + bias;
        cand_v64[(size_t)b1 * MCAND + pos1] = v1;
        cand_v32[(size_t)b1 * MCAND + pos1] = (float)v1;
      }
    }
  }
}

// ---------------- flag near-ties (fp64 sort, adjacent-gap test) ----------------
__global__ __launch_bounds__(256) void k_flag(
    const double* __restrict__ cand_v64, const int* __restrict__ cand_idx,
    const int* __restrict__ cand_cnt, int* __restrict__ dcnt,
    int* __restrict__ dlist)
{
  __shared__ double v[MCAND];
  __shared__ int id[MCAND];
  __shared__ double sv[MCAND];
  __shared__ int sp[MCAND];
  const int b = blockIdx.x;
  const int t = threadIdx.x;
  const int c = cand_cnt[b];
  if (c < 2) return;
  if (t < c) {
    v[t] = cand_v64[(size_t)b * MCAND + t];
    id[t] = cand_idx[(size_t)b * MCAND + t];
  }
  __syncthreads();
  if (t < c) {
    const double vt = v[t];
    const int it = id[t];
    int r = 0;
    for (int j = 0; j < c; ++j) {
      const double vj = v[j];
      if (vj > vt || (vj == vt && id[j] < it)) ++r;
    }
    sv[r] = vt;
    sp[r] = t;
  }
  __syncthreads();
  if (t == 0) {
    for (int r = 0; r < c - 1; ++r) {
      const double a = fabs(sv[r]), bb = fabs(sv[r + 1]);
      const double m = a > bb ? a : bb;
      const double thr = m * 7.7e-6 + 1e-7;   // ~64 fp32-ulp relative
      if (sv[r] - sv[r + 1] <= thr) {
        const int base = atomicAdd(dcnt, 2);
        if (base + 1 < DCAP) {
          dlist[base] = (b << 8) | sp[r];
          dlist[base + 1] = (b << 8) | sp[r + 1];
        }
      }
    }
  }
}

// ---------------- bit-exact BLIS recompute for disputed candidates only ----------------
__global__ __launch_bounds__(64) void k_blas_small(
    const float* __restrict__ x, const float* __restrict__ W,
    const float* __restrict__ b_enc, const int* __restrict__ cand_idx,
    const int* __restrict__ dcnt, const int* __restrict__ dlist,
    float* __restrict__ cand_v32)
{
  int n = *dcnt;
  if (n > DCAP) n = DCAP;
  if (n == 0) return;
  const int lane = threadIdx.x;
  const int eg = lane >> 3;          // entry slot within wave, 0..7
  const int p = lane & 7;            // panel index
  for (int i0 = blockIdx.x * 8; i0 < n; i0 += gridDim.x * 8) {
    const int i = i0 + eg;
    const bool live = (i < n);
    const int ent = dlist[live ? i : 0];
    const int b = ent >> 8;
    const int pos = ent & 255;
    const int f = cand_idx[(size_t)b * MCAND + pos];
    const float* xp = x + (size_t)b * Dn + p * KCB;
    const float* wp = W + (size_t)f * Dn + p * KCB;

    float pp = 0.0f;
    for (int d = 0; d < KCB; d += 4) {
      const f32x4 xv = *(const f32x4*)(xp + d);
      const f32x4 wv = *(const f32x4*)(wp + d);
      pp = __builtin_fmaf(xv[0], wv[0], pp);
      pp = __builtin_fmaf(xv[1], wv[1], pp);
      pp = __builtin_fmaf(xv[2], wv[2], pp);
      pp = __builtin_fmaf(xv[3], wv[3], pp);
    }
    const int base = lane & ~7;
    float h = __shfl(pp, base);
    {
#pragma clang fp contract(off)
      h = h + __shfl(pp, base + 1);
      h = h + __shfl(pp, base + 2);
      h = h + __shfl(pp, base + 3);
      h = h + __shfl(pp, base + 4);
      h = h + __shfl(pp, base + 5);
      h = h + __shfl(pp, base + 6);
      h = h + __shfl(pp, base + 7);
      if (live && p == 0)
        cand_v32[(size_t)b * MCAND + pos] = h + b_enc[f];
    }
  }
}

// ---------------- ranking: (fp32 value desc, index ASC on exact ties) ----------------
__global__ __launch_bounds__(256) void k_final_rank(
    const int* __restrict__ cand_idx, const float* __restrict__ cand_val,
    const int* __restrict__ cand_cnt, float* __restrict__ out_idx_f,
    int* __restrict__ top_idx, float* __restrict__ top_val)
{
  __shared__ float v[MCAND];
  __shared__ int id[MCAND];
  const int b = blockIdx.x;
  const int t = threadIdx.x;
  const int c = cand_cnt[b];
  if (t < c) {
    v[t] = cand_val[(size_t)b * MCAND + t];
    id[t] = cand_idx[(size_t)b * MCAND + t];
  }
  __syncthreads();
  if (t < c) {
    const float vt = v[t];
    const int it = id[t];
    int r = 0;
    for (int j = 0; j < c; ++j) {
      const float vj = v[j];
      if (vj > vt || (vj == vt && id[j] < it)) ++r;
    }
    if (r < KTOP) {
      out_idx_f[(size_t)b * KTOP + r] = (float)it;  // harness reads indices as f32
      top_idx[(size_t)b * KTOP + r] = it;
      top_val[(size_t)b * KTOP + r] = vt > 0.0f ? vt : 0.0f;  // relu after top-k
    }
  }
}

// ---------------- scatter relu'd values into zeroed h_sparse ----------------
__global__ __launch_bounds__(256) void k_scatter(const int* __restrict__ top_idx,
                                                 const float* __restrict__ top_val,
                                                 float* __restrict__ Hs)
{
  const int i = blockIdx.x * 256 + threadIdx.x;
  const int b = i >> 6;
  Hs[(size_t)b * Fn + top_idx[i]] = top_val[i];
}

// ---------------- W_dec (D,F) fp32 -> W_decT (F,D) bf16 ----------------
__global__ __launch_bounds__(256) void k_transpose(const float* __restrict__ Wd,
                                                   unsigned short* __restrict__ WdT)
{
  __shared__ float tile[64][65];
  const int f0 = blockIdx.x * 64;
  const int d0 = blockIdx.y * 64;
  const int t = threadIdx.x;
#pragma unroll
  for (int rr = 0; rr < 4; ++rr) {
    const int d = rr * 16 + (t >> 4);
    const int f = (t & 15) * 4;
    const float4 v = *(const float4*)(Wd + (size_t)(d0 + d) * Fn + f0 + f);
    tile[d][f] = v.x; tile[d][f + 1] = v.y; tile[d][f + 2] = v.z; tile[d][f + 3] = v.w;
  }
  __syncthreads();
#pragma unroll
  for (int rr = 0; rr < 2; ++rr) {
    const int f = rr * 32 + (t >> 3);
    const int d8 = (t & 7) * 8;
    uint4 o;
    unsigned int u[4];
#pragma unroll
    for (int q = 0; q < 4; ++q) {
      const unsigned int lo = f2bf(tile[d8 + q * 2][f]);
      const unsigned int hi = f2bf(tile[d8 + q * 2 + 1][f]);
      u[q] = lo | (hi << 16);
    }
    o.x = u[0]; o.y = u[1]; o.z = u[2]; o.w = u[3];
    *(uint4*)(WdT + (size_t)(f0 + f) * Dn + d0 + d8) = o;
  }
}

// ---------------- sparse decode: x_hat[b,:] = sum_k v_k * W_decT[idx_k,:] + b_dec ----------------
__global__ __launch_bounds__(256) void k_decode(
    const int* __restrict__ top_idx, const float* __restrict__ top_val,
    const unsigned short* __restrict__ WdT, const float* __restrict__ b_dec,
    float* __restrict__ xhat)
{
  __shared__ int sidx[KTOP];
  __shared__ float sval[KTOP];
  const int b = blockIdx.x;
  const int t = threadIdx.x;
  if (t < KTOP) {
    sidx[t] = top_idx[(size_t)b * KTOP + t];
    sval[t] = top_val[(size_t)b * KTOP + t];
  }
  __syncthreads();
  float acc[16];
#pragma unroll
  for (int q = 0; q < 16; ++q) acc[q] = 0.0f;
  const int dbase = t * 16;
  for (int k = 0; k < KTOP; ++k) {
    const int f = sidx[k];
    const float vv = sval[k];
    const unsigned short* wp = WdT + (size_t)f * Dn + dbase;
    const u16x8 w0 = *(const u16x8*)wp;
    const u16x8 w1 = *(const u16x8*)(wp + 8);
#pragma unroll
    for (int q = 0; q < 8; ++q) {
      acc[q]     += vv * bf2f(w0[q]);
      acc[8 + q] += vv * bf2f(w1[q]);
    }
  }
#pragma unroll
  for (int q = 0; q < 16; ++q) acc[q] += b_dec[dbase + q];
  float* op = xhat + (size_t)b * Dn + dbase;
#pragma unroll
  for (int qq = 0; qq < 4; ++qq)
    *(float4*)(op + qq * 4) = make_float4(acc[qq * 4], acc[qq * 4 + 1],
                                          acc[qq * 4 + 2], acc[qq * 4 + 3]);
}

// ---------------- workspace layout ----------------
static constexpr size_t OFF_WBF   = 0;                                   // F*D bf16 (W_enc_bf16, later W_decT)
static constexpr size_t OFF_XBF   = OFF_WBF + (size_t)Fn * Dn * 2;       // B*D bf16
static constexpr size_t OFF_CIDX  = OFF_XBF + (size_t)Bn * Dn * 2;       // B*MCAND int
static constexpr size_t OFF_CV32  = OFF_CIDX + (size_t)Bn * MCAND * 4;   // B*MCAND float
static constexpr size_t OFF_CV64  = OFF_CV32 + (size_t)Bn * MCAND * 4;   // B*MCAND double
static constexpr size_t OFF_CCNT  = OFF_CV64 + (size_t)Bn * MCAND * 8;   // B int
static constexpr size_t OFF_FCNT  = OFF_CCNT + (size_t)Bn * 4;           // F int (adjacent)
static constexpr size_t OFF_DCNT  = OFF_FCNT + (size_t)Fn * 4;           // 16 int (adjacent)
static constexpr size_t OFF_DLIST = OFF_DCNT + 64;                       // DCAP int
static constexpr size_t OFF_FLIST = OFF_DLIST + (size_t)DCAP * 4;        // F*64 int
static constexpr size_t OFF_TIDX  = OFF_FLIST + (size_t)Fn * 64 * 4;     // B*64 int
static constexpr size_t OFF_TVAL  = OFF_TIDX + (size_t)Bn * KTOP * 4;    // B*64 float

extern "C" void kernel_launch(void* const* d_in, const int* in_sizes, int n_in,
                              void* d_out, int out_size, void* d_ws, size_t ws_size,
                              hipStream_t stream) {
  const float* x     = (const float*)d_in[0];
  const float* W_enc = (const float*)d_in[1];
  const float* b_enc = (const float*)d_in[2];
  const float* W_dec = (const float*)d_in[3];
  const float* b_dec = (const float*)d_in[4];

  char* ws = (char*)d_ws;
  unsigned short* WBF  = (unsigned short*)(ws + OFF_WBF);
  unsigned short* XBF  = (unsigned short*)(ws + OFF_XBF);
  int*    CIDX  = (int*)(ws + OFF_CIDX);
  float*  CV32  = (float*)(ws + OFF_CV32);
  double* CV64  = (double*)(ws + OFF_CV64);
  int*    CCNT  = (int*)(ws + OFF_CCNT);
  int*    FCNT  = (int*)(ws + OFF_FCNT);
  int*    DCNT  = (int*)(ws + OFF_DCNT);
  int*    DLIST = (int*)(ws + OFF_DLIST);
  int*    FLIST = (int*)(ws + OFF_FLIST);
  int*    TIDX  = (int*)(ws + OFF_TIDX);
  float*  TVAL  = (float*)(ws + OFF_TVAL);

  float* XHAT = (float*)d_out;
  float* H    = XHAT + (size_t)Bn * Dn;       // h_sparse region (fp32)
  unsigned short* Hb = (unsigned short*)H;    // bf16 dense-h scratch (first half)
  float* OIDX = H + (size_t)Bn * Fn;

  // zero the atomic counters (CCNT, FCNT, DCNT are adjacent)
  hipMemsetAsync(CCNT, 0, (size_t)(Bn + Fn + 16) * sizeof(int), stream);

  // fp32 -> bf16
  {
    const long n8x = (long)Bn * Dn / 8;
    k_cvt_bf16<<<(n8x + 255) / 256, 256, 0, stream>>>(x, XBF, n8x);
    const long n8w = (long)Fn * Dn / 8;
    k_cvt_bf16<<<(n8w + 255) / 256, 256, 0, stream>>>(W_enc, WBF, n8w);
  }

  // encode: dense h (approx, bf16 MFMA, bf16 store) into out's h region
  dim3 gg(Bn / 256, Fn / 128);
  k_gemm_encode<<<gg, 512, 0, stream>>>(XBF, WBF, b_enc, Hb);

  // candidate selection + feature-major lists (LDS row cache, margin 0.08)
  k_topk_select<<<Bn, 256, 0, stream>>>(Hb, CIDX, CCNT, FCNT, FLIST, CV32, CV64);

  // fp64 coalesced recompute of all candidates (2-candidate interleave)
  k_exact_rank<<<Fn / 4, 256, 0, stream>>>(x, W_enc, b_enc, FCNT, FLIST, CV32, CV64);

  // flag near-tie adjacent pairs (fp64 order)
  k_flag<<<Bn, 256, 0, stream>>>(CV64, CIDX, CCNT, DCNT, DLIST);

  // bit-exact BLIS recompute for disputed candidates only
  k_blas_small<<<32, 64, 0, stream>>>(x, W_enc, b_enc, CIDX, DCNT, DLIST, CV32);

  // ranking (value desc, index asc on ties); writes output indices (as float)
  k_final_rank<<<Bn, 256, 0, stream>>>(CIDX, CV32, CCNT, OIDX, TIDX, TVAL);

  // zero h_sparse then scatter relu'd values
  hipMemsetAsync(H, 0, (size_t)Bn * Fn * sizeof(float), stream);
  k_scatter<<<(Bn * KTOP) / 256, 256, 0, stream>>>(TIDX, TVAL, H);

  // transpose W_dec into bf16 (F,D)  (reuses WBF region; encode GEMM is done)
  k_transpose<<<dim3(Fn / 64, Dn / 64), 256, 0, stream>>>(W_dec, WBF);

  // sparse decode
  k_decode<<<Bn, 256, 0, stream>>>(TIDX, TVAL, WBF, b_dec, XHAT);
}

// Round 24
// 1783.061 us; speedup vs baseline: 1.1149x; 1.1149x over previous
//
#include <hip/hip_runtime.h>
#include <cstdint>

#define Bn 2048
#define Dn 4096
#define Fn 32768
#define KTOP 64
#define MCAND 192
#define KCB 512    // BLIS/AOCL zen sgemm KC
#define DCAP 4096  // disputed-candidate list capacity

typedef __attribute__((ext_vector_type(8))) short short8;
typedef __attribute__((ext_vector_type(4))) float f32x4;
typedef __attribute__((ext_vector_type(8))) unsigned short u16x8;

typedef __attribute__((address_space(1))) void as1_void;
typedef __attribute__((address_space(3))) void as3_void;

__device__ __forceinline__ void gload_lds16(const void* g, void* l) {
  __builtin_amdgcn_global_load_lds((const as1_void*)(uintptr_t)g,
                                   (as3_void*)(unsigned int)(uintptr_t)l,
                                   16, 0, 0);
}

__device__ __forceinline__ float bf2f(unsigned short u) {
  unsigned int x = ((unsigned int)u) << 16;
  return __builtin_bit_cast(float, x);
}
__device__ __forceinline__ unsigned short f2bf(float f) {
  unsigned int x = __builtin_bit_cast(unsigned int, f);
  x = x + 0x7fffu + ((x >> 16) & 1u);
  return (unsigned short)(x >> 16);
}

// ---------------- fp32 -> bf16 convert, 8 elems/thread ----------------
__global__ __launch_bounds__(256) void k_cvt_bf16(const float* __restrict__ in,
                                                  unsigned short* __restrict__ out,
                                                  long n8) {
  const long i = (long)blockIdx.x * 256 + threadIdx.x;
  if (i >= n8) return;
  const float4 a = *(const float4*)(in + i * 8);
  const float4 b = *(const float4*)(in + i * 8 + 4);
  uint4 o;
  o.x = (unsigned int)f2bf(a.x) | ((unsigned int)f2bf(a.y) << 16);
  o.y = (unsigned int)f2bf(a.z) | ((unsigned int)f2bf(a.w) << 16);
  o.z = (unsigned int)f2bf(b.x) | ((unsigned int)f2bf(b.y) << 16);
  o.w = (unsigned int)f2bf(b.z) | ((unsigned int)f2bf(b.w) << 16);
  *(uint4*)(out + i * 8) = o;
}

// ---------------- encoder GEMM: Hb[M,N] (bf16) = Xbf[M,K] * Wbf[N,K]^T + bias ----------------
// BM=256 x BN=128, BK=64, 512 threads (8 waves = 4m x 2n). R20/R22-verified
// structure (MfmaUtil 50%). bf16 epilogue store.
__global__ __launch_bounds__(512) void k_gemm_encode(
    const unsigned short* __restrict__ A,   // M x K bf16 (x)
    const unsigned short* __restrict__ Bm,  // N x K bf16 (W_enc)
    const float* __restrict__ bias,         // N (b_enc)
    unsigned short* __restrict__ Hb)        // M x N bf16
{
  constexpr int Kd = Dn;
  constexpr int Nn = Fn;
  __shared__ __align__(16) unsigned short lA[256 * 64];  // 32 KB
  __shared__ __align__(16) unsigned short lB[128 * 64];  // 16 KB
  const int tid = threadIdx.x;
  const int lane = tid & 63;
  const int wid = tid >> 6;                 // 0..7
  const int wm = wid >> 1, wn = wid & 1;    // 4 x 2 wave grid
  const int m0 = blockIdx.x * 256;
  const int n0 = blockIdx.y * 128;

  const int srow = lane >> 3;                   // 0..7 row within 8-row section
  const int csw = ((lane & 7) ^ srow) * 8;      // swizzled k-element offset (bf16 units)

  f32x4 acc[4][4] = {};

  for (int kt = 0; kt < Kd; kt += 64) {
    // 48 sections (32 A + 16 B), 6 per wave; section = 8 rows x 64 cols
#pragma unroll
    for (int s = wid; s < 48; s += 8) {
      if (s < 32) {
        const int r = s * 8 + srow;
        gload_lds16(A + (size_t)(m0 + r) * Kd + kt + csw, (char*)lA + s * 1024);
      } else {
        const int s2 = s - 32;
        const int r = s2 * 8 + srow;
        gload_lds16(Bm + (size_t)(n0 + r) * Kd + kt + csw, (char*)lB + s2 * 1024);
      }
    }
    __syncthreads();
#pragma unroll
    for (int kk = 0; kk < 2; ++kk) {
      short8 af[4], bfr[4];
      const int c16 = (kk * 4 + (lane >> 4)) ^ (lane & 7);
#pragma unroll
      for (int i = 0; i < 4; ++i) {
        const int row = wm * 64 + i * 16 + (lane & 15);
        af[i] = *(const short8*)((const char*)lA + row * 128 + c16 * 16);
      }
#pragma unroll
      for (int j = 0; j < 4; ++j) {
        const int row = wn * 64 + j * 16 + (lane & 15);
        bfr[j] = *(const short8*)((const char*)lB + row * 128 + c16 * 16);
      }
#pragma unroll
      for (int i = 0; i < 4; ++i)
#pragma unroll
        for (int j = 0; j < 4; ++j)
          acc[i][j] = __builtin_amdgcn_mfma_f32_16x16x32_bf16(af[i], bfr[j], acc[i][j], 0, 0, 0);
    }
    __syncthreads();
  }

  const int lr = (lane >> 4) * 4;
  const int lc = lane & 15;
#pragma unroll
  for (int i = 0; i < 4; ++i) {
    const int grow = m0 + wm * 64 + i * 16 + lr;
#pragma unroll
    for (int j = 0; j < 4; ++j) {
      const int gcol = n0 + wn * 64 + j * 16 + lc;
      const float bv = bias[gcol];
#pragma unroll
      for (int r = 0; r < 4; ++r)
        Hb[(size_t)(grow + r) * Nn + gcol] = f2bf(acc[i][j][r] + bv);
    }
  }
}

// ---------------- per-row candidate selection via LDS histogram (bf16 H) ----------------
// R22-proven version (R23's 64KB LDS row-cache capped occupancy and regressed).
// Margin 0.08 covers bf16-GEMM tail (~0.03) + bf16-H quantization (<=0.0156).
__global__ __launch_bounds__(256) void k_topk_select(
    const unsigned short* __restrict__ Hb, int* __restrict__ cand_idx,
    int* __restrict__ cand_cnt, int* __restrict__ feat_cnt,
    int* __restrict__ feat_list, float* __restrict__ cand_v32,
    double* __restrict__ cand_v64)
{
  __shared__ int hist[2048];
  __shared__ float s_tau;
  __shared__ int s_cnt;
  const int b = blockIdx.x;
  const int t = threadIdx.x;
  for (int i = t; i < 2048; i += 256) hist[i] = 0;
  if (t == 0) s_cnt = 0;
  __syncthreads();
  const unsigned short* row = Hb + (size_t)b * Fn;
  for (int i = t * 8; i < Fn; i += 2048) {
    const u16x8 hv = *(const u16x8*)(row + i);
#pragma unroll
    for (int q = 0; q < 8; ++q) {
      const float h = bf2f(hv[q]);
      if (h > 0.0f) {
        int bin = (int)(h * 128.0f);
        if (bin > 2047) bin = 2047;
        atomicAdd(&hist[bin], 1);
      }
    }
  }
  __syncthreads();
  if (t == 0) {
    int total = 0;
    int bin = 2047;
    for (; bin > 0; --bin) {
      total += hist[bin];
      if (total >= KTOP) break;
    }
    s_tau = (float)bin * (1.0f / 128.0f) - 0.08f;
  }
  __syncthreads();
  const float tau = s_tau;
  for (int i = t * 8; i < Fn; i += 2048) {
    const u16x8 hv = *(const u16x8*)(row + i);
#pragma unroll
    for (int q = 0; q < 8; ++q) {
      const float h = bf2f(hv[q]);
      if (h >= tau) {
        const int pos = atomicAdd(&s_cnt, 1);
        if (pos < MCAND) {
          cand_idx[(size_t)b * MCAND + pos] = i + q;
          const int slot = atomicAdd(&feat_cnt[i + q], 1);
          if (slot < 64) feat_list[(size_t)(i + q) * 64 + slot] = (b << 8) | pos;
          else {  // overflow sentinel, never stale
            cand_v32[(size_t)b * MCAND + pos] = -1e30f;
            cand_v64[(size_t)b * MCAND + pos] = -1e30;
          }
        }
      }
    }
  }
  __syncthreads();
  if (t == 0) cand_cnt[b] = s_cnt < MCAND ? s_cnt : MCAND;
}

// ---------------- fp64 coalesced recompute (all candidates) ----------------
// R22-proven version (R23's 2-candidate interleave doubled fp64 issue and regressed).
__global__ __launch_bounds__(256) void k_exact_rank(
    const float* __restrict__ x, const float* __restrict__ W,
    const float* __restrict__ b_enc, const int* __restrict__ feat_cnt,
    const int* __restrict__ feat_list, float* __restrict__ cand_v32,
    double* __restrict__ cand_v64)
{
  const int f = blockIdx.x * 4 + (threadIdx.x >> 6);
  const int lane = threadIdx.x & 63;
  int c = feat_cnt[f];
  if (c > 64) c = 64;
  if (c == 0) return;
  const float* wr = W + (size_t)f * Dn;
  const double bias = (double)b_enc[f];
  for (int e = 0; e < c; ++e) {
    const int ent = feat_list[(size_t)f * 64 + e];
    const int b = ent >> 8;
    const int pos = ent & 255;
    const float* xr = x + (size_t)b * Dn;
    double s = 0.0;
#pragma unroll
    for (int k = 0; k < Dn / 256; ++k) {
      const f32x4 xv = *(const f32x4*)(xr + k * 256 + lane * 4);
      const f32x4 wv = *(const f32x4*)(wr + k * 256 + lane * 4);
      s = fma((double)xv[0], (double)wv[0], s);
      s = fma((double)xv[1], (double)wv[1], s);
      s = fma((double)xv[2], (double)wv[2], s);
      s = fma((double)xv[3], (double)wv[3], s);
    }
    for (int o = 32; o > 0; o >>= 1) s += __shfl_down(s, o);
    if (lane == 0) {
      const double v = s + bias;
      cand_v64[(size_t)b * MCAND + pos] = v;
      cand_v32[(size_t)b * MCAND + pos] = (float)v;
    }
  }
}

// ---------------- flag near-ties (fp64 sort, adjacent-gap test) ----------------
__global__ __launch_bounds__(256) void k_flag(
    const double* __restrict__ cand_v64, const int* __restrict__ cand_idx,
    const int* __restrict__ cand_cnt, int* __restrict__ dcnt,
    int* __restrict__ dlist)
{
  __shared__ double v[MCAND];
  __shared__ int id[MCAND];
  __shared__ double sv[MCAND];
  __shared__ int sp[MCAND];
  const int b = blockIdx.x;
  const int t = threadIdx.x;
  const int c = cand_cnt[b];
  if (c < 2) return;
  if (t < c) {
    v[t] = cand_v64[(size_t)b * MCAND + t];
    id[t] = cand_idx[(size_t)b * MCAND + t];
  }
  __syncthreads();
  if (t < c) {
    const double vt = v[t];
    const int it = id[t];
    int r = 0;
    for (int j = 0; j < c; ++j) {
      const double vj = v[j];
      if (vj > vt || (vj == vt && id[j] < it)) ++r;
    }
    sv[r] = vt;
    sp[r] = t;
  }
  __syncthreads();
  if (t == 0) {
    for (int r = 0; r < c - 1; ++r) {
      const double a = fabs(sv[r]), bb = fabs(sv[r + 1]);
      const double m = a > bb ? a : bb;
      const double thr = m * 7.7e-6 + 1e-7;   // ~64 fp32-ulp relative
      if (sv[r] - sv[r + 1] <= thr) {
        const int base = atomicAdd(dcnt, 2);
        if (base + 1 < DCAP) {
          dlist[base] = (b << 8) | sp[r];
          dlist[base + 1] = (b << 8) | sp[r + 1];
        }
      }
    }
  }
}

// ---------------- bit-exact BLIS recompute for disputed candidates only ----------------
__global__ __launch_bounds__(64) void k_blas_small(
    const float* __restrict__ x, const float* __restrict__ W,
    const float* __restrict__ b_enc, const int* __restrict__ cand_idx,
    const int* __restrict__ dcnt, const int* __restrict__ dlist,
    float* __restrict__ cand_v32)
{
  int n = *dcnt;
  if (n > DCAP) n = DCAP;
  if (n == 0) return;
  const int lane = threadIdx.x;
  const int eg = lane >> 3;          // entry slot within wave, 0..7
  const int p = lane & 7;            // panel index
  for (int i0 = blockIdx.x * 8; i0 < n; i0 += gridDim.x * 8) {
    const int i = i0 + eg;
    const bool live = (i < n);
    const int ent = dlist[live ? i : 0];
    const int b = ent >> 8;
    const int pos = ent & 255;
    const int f = cand_idx[(size_t)b * MCAND + pos];
    const float* xp = x + (size_t)b * Dn + p * KCB;
    const float* wp = W + (size_t)f * Dn + p * KCB;

    float pp = 0.0f;
    for (int d = 0; d < KCB; d += 4) {
      const f32x4 xv = *(const f32x4*)(xp + d);
      const f32x4 wv = *(const f32x4*)(wp + d);
      pp = __builtin_fmaf(xv[0], wv[0], pp);
      pp = __builtin_fmaf(xv[1], wv[1], pp);
      pp = __builtin_fmaf(xv[2], wv[2], pp);
      pp = __builtin_fmaf(xv[3], wv[3], pp);
    }
    const int base = lane & ~7;
    float h = __shfl(pp, base);
    {
#pragma clang fp contract(off)
      h = h + __shfl(pp, base + 1);
      h = h + __shfl(pp, base + 2);
      h = h + __shfl(pp, base + 3);
      h = h + __shfl(pp, base + 4);
      h = h + __shfl(pp, base + 5);
      h = h + __shfl(pp, base + 6);
      h = h + __shfl(pp, base + 7);
      if (live && p == 0)
        cand_v32[(size_t)b * MCAND + pos] = h + b_enc[f];
    }
  }
}

// ---------------- ranking: (fp32 value desc, index ASC on exact ties) ----------------
__global__ __launch_bounds__(256) void k_final_rank(
    const int* __restrict__ cand_idx, const float* __restrict__ cand_val,
    const int* __restrict__ cand_cnt, float* __restrict__ out_idx_f,
    int* __restrict__ top_idx, float* __restrict__ top_val)
{
  __shared__ float v[MCAND];
  __shared__ int id[MCAND];
  const int b = blockIdx.x;
  const int t = threadIdx.x;
  const int c = cand_cnt[b];
  if (t < c) {
    v[t] = cand_val[(size_t)b * MCAND + t];
    id[t] = cand_idx[(size_t)b * MCAND + t];
  }
  __syncthreads();
  if (t < c) {
    const float vt = v[t];
    const int it = id[t];
    int r = 0;
    for (int j = 0; j < c; ++j) {
      const float vj = v[j];
      if (vj > vt || (vj == vt && id[j] < it)) ++r;
    }
    if (r < KTOP) {
      out_idx_f[(size_t)b * KTOP + r] = (float)it;  // harness reads indices as f32
      top_idx[(size_t)b * KTOP + r] = it;
      top_val[(size_t)b * KTOP + r] = vt > 0.0f ? vt : 0.0f;  // relu after top-k
    }
  }
}

// ---------------- scatter relu'd values into zeroed h_sparse ----------------
__global__ __launch_bounds__(256) void k_scatter(const int* __restrict__ top_idx,
                                                 const float* __restrict__ top_val,
                                                 float* __restrict__ Hs)
{
  const int i = blockIdx.x * 256 + threadIdx.x;
  const int b = i >> 6;
  Hs[(size_t)b * Fn + top_idx[i]] = top_val[i];
}

// ---------------- W_dec (D,F) fp32 -> W_decT (F,D) bf16 ----------------
__global__ __launch_bounds__(256) void k_transpose(const float* __restrict__ Wd,
                                                   unsigned short* __restrict__ WdT)
{
  __shared__ float tile[64][65];
  const int f0 = blockIdx.x * 64;
  const int d0 = blockIdx.y * 64;
  const int t = threadIdx.x;
#pragma unroll
  for (int rr = 0; rr < 4; ++rr) {
    const int d = rr * 16 + (t >> 4);
    const int f = (t & 15) * 4;
    const float4 v = *(const float4*)(Wd + (size_t)(d0 + d) * Fn + f0 + f);
    tile[d][f] = v.x; tile[d][f + 1] = v.y; tile[d][f + 2] = v.z; tile[d][f + 3] = v.w;
  }
  __syncthreads();
#pragma unroll
  for (int rr = 0; rr < 2; ++rr) {
    const int f = rr * 32 + (t >> 3);
    const int d8 = (t & 7) * 8;
    uint4 o;
    unsigned int u[4];
#pragma unroll
    for (int q = 0; q < 4; ++q) {
      const unsigned int lo = f2bf(tile[d8 + q * 2][f]);
      const unsigned int hi = f2bf(tile[d8 + q * 2 + 1][f]);
      u[q] = lo | (hi << 16);
    }
    o.x = u[0]; o.y = u[1]; o.z = u[2]; o.w = u[3];
    *(uint4*)(WdT + (size_t)(f0 + f) * Dn + d0 + d8) = o;
  }
}

// ---------------- sparse decode: x_hat[b,:] = sum_k v_k * W_decT[idx_k,:] + b_dec ----------------
__global__ __launch_bounds__(256) void k_decode(
    const int* __restrict__ top_idx, const float* __restrict__ top_val,
    const unsigned short* __restrict__ WdT, const float* __restrict__ b_dec,
    float* __restrict__ xhat)
{
  __shared__ int sidx[KTOP];
  __shared__ float sval[KTOP];
  const int b = blockIdx.x;
  const int t = threadIdx.x;
  if (t < KTOP) {
    sidx[t] = top_idx[(size_t)b * KTOP + t];
    sval[t] = top_val[(size_t)b * KTOP + t];
  }
  __syncthreads();
  float acc[16];
#pragma unroll
  for (int q = 0; q < 16; ++q) acc[q] = 0.0f;
  const int dbase = t * 16;
  for (int k = 0; k < KTOP; ++k) {
    const int f = sidx[k];
    const float vv = sval[k];
    const unsigned short* wp = WdT + (size_t)f * Dn + dbase;
    const u16x8 w0 = *(const u16x8*)wp;
    const u16x8 w1 = *(const u16x8*)(wp + 8);
#pragma unroll
    for (int q = 0; q < 8; ++q) {
      acc[q]     += vv * bf2f(w0[q]);
      acc[8 + q] += vv * bf2f(w1[q]);
    }
  }
#pragma unroll
  for (int q = 0; q < 16; ++q) acc[q] += b_dec[dbase + q];
  float* op = xhat + (size_t)b * Dn + dbase;
#pragma unroll
  for (int qq = 0; qq < 4; ++qq)
    *(float4*)(op + qq * 4) = make_float4(acc[qq * 4], acc[qq * 4 + 1],
                                          acc[qq * 4 + 2], acc[qq * 4 + 3]);
}

// ---------------- workspace layout ----------------
static constexpr size_t OFF_WBF   = 0;                                   // F*D bf16 (W_enc_bf16, later W_decT)
static constexpr size_t OFF_XBF   = OFF_WBF + (size_t)Fn * Dn * 2;       // B*D bf16
static constexpr size_t OFF_CIDX  = OFF_XBF + (size_t)Bn * Dn * 2;       // B*MCAND int
static constexpr size_t OFF_CV32  = OFF_CIDX + (size_t)Bn * MCAND * 4;   // B*MCAND float
static constexpr size_t OFF_CV64  = OFF_CV32 + (size_t)Bn * MCAND * 4;   // B*MCAND double
static constexpr size_t OFF_CCNT  = OFF_CV64 + (size_t)Bn * MCAND * 8;   // B int
static constexpr size_t OFF_FCNT  = OFF_CCNT + (size_t)Bn * 4;           // F int (adjacent)
static constexpr size_t OFF_DCNT  = OFF_FCNT + (size_t)Fn * 4;           // 16 int (adjacent)
static constexpr size_t OFF_DLIST = OFF_DCNT + 64;                       // DCAP int
static constexpr size_t OFF_FLIST = OFF_DLIST + (size_t)DCAP * 4;        // F*64 int
static constexpr size_t OFF_TIDX  = OFF_FLIST + (size_t)Fn * 64 * 4;     // B*64 int
static constexpr size_t OFF_TVAL  = OFF_TIDX + (size_t)Bn * KTOP * 4;    // B*64 float

extern "C" void kernel_launch(void* const* d_in, const int* in_sizes, int n_in,
                              void* d_out, int out_size, void* d_ws, size_t ws_size,
                              hipStream_t stream) {
  const float* x     = (const float*)d_in[0];
  const float* W_enc = (const float*)d_in[1];
  const float* b_enc = (const float*)d_in[2];
  const float* W_dec = (const float*)d_in[3];
  const float* b_dec = (const float*)d_in[4];

  char* ws = (char*)d_ws;
  unsigned short* WBF  = (unsigned short*)(ws + OFF_WBF);
  unsigned short* XBF  = (unsigned short*)(ws + OFF_XBF);
  int*    CIDX  = (int*)(ws + OFF_CIDX);
  float*  CV32  = (float*)(ws + OFF_CV32);
  double* CV64  = (double*)(ws + OFF_CV64);
  int*    CCNT  = (int*)(ws + OFF_CCNT);
  int*    FCNT  = (int*)(ws + OFF_FCNT);
  int*    DCNT  = (int*)(ws + OFF_DCNT);
  int*    DLIST = (int*)(ws + OFF_DLIST);
  int*    FLIST = (int*)(ws + OFF_FLIST);
  int*    TIDX  = (int*)(ws + OFF_TIDX);
  float*  TVAL  = (float*)(ws + OFF_TVAL);

  float* XHAT = (float*)d_out;
  float* H    = XHAT + (size_t)Bn * Dn;       // h_sparse region (fp32)
  unsigned short* Hb = (unsigned short*)H;    // bf16 dense-h scratch (first half)
  float* OIDX = H + (size_t)Bn * Fn;

  // zero the atomic counters (CCNT, FCNT, DCNT are adjacent)
  hipMemsetAsync(CCNT, 0, (size_t)(Bn + Fn + 16) * sizeof(int), stream);

  // fp32 -> bf16
  {
    const long n8x = (long)Bn * Dn / 8;
    k_cvt_bf16<<<(n8x + 255) / 256, 256, 0, stream>>>(x, XBF, n8x);
    const long n8w = (long)Fn * Dn / 8;
    k_cvt_bf16<<<(n8w + 255) / 256, 256, 0, stream>>>(W_enc, WBF, n8w);
  }

  // encode: dense h (approx, bf16 MFMA, bf16 store) into out's h region
  dim3 gg(Bn / 256, Fn / 128);
  k_gemm_encode<<<gg, 512, 0, stream>>>(XBF, WBF, b_enc, Hb);

  // candidate selection + feature-major lists (margin 0.08)
  k_topk_select<<<Bn, 256, 0, stream>>>(Hb, CIDX, CCNT, FCNT, FLIST, CV32, CV64);

  // fp64 coalesced recompute of all candidates
  k_exact_rank<<<Fn / 4, 256, 0, stream>>>(x, W_enc, b_enc, FCNT, FLIST, CV32, CV64);

  // flag near-tie adjacent pairs (fp64 order)
  k_flag<<<Bn, 256, 0, stream>>>(CV64, CIDX, CCNT, DCNT, DLIST);

  // bit-exact BLIS recompute for disputed candidates only
  k_blas_small<<<32, 64, 0, stream>>>(x, W_enc, b_enc, CIDX, DCNT, DLIST, CV32);

  // ranking (value desc, index asc on ties); writes output indices (as float)
  k_final_rank<<<Bn, 256, 0, stream>>>(CIDX, CV32, CCNT, OIDX, TIDX, TVAL);

  // zero h_sparse then scatter relu'd values
  hipMemsetAsync(H, 0, (size_t)Bn * Fn * sizeof(float), stream);
  k_scatter<<<(Bn * KTOP) / 256, 256, 0, stream>>>(TIDX, TVAL, H);

  // transpose W_dec into bf16 (F,D)  (reuses WBF region; encode GEMM is done)
  k_transpose<<<dim3(Fn / 64, Dn / 64), 256, 0, stream>>>(W_dec, WBF);

  // sparse decode
  k_decode<<<Bn, 256, 0, stream>>>(TIDX, TVAL, WBF, b_dec, XHAT);
}